// Round 3
// baseline (190.611 us; speedup 1.0000x reference)
//
#include <hip/hip_runtime.h>

typedef unsigned int uint;
typedef unsigned short ushort;
typedef __attribute__((ext_vector_type(8))) short short8;   // 8 bf16 = 4 VGPRs
typedef __attribute__((ext_vector_type(4))) float floatx4;  // MFMA C/D

#define N_NODES 50000
#define N_EDGES 1600000
#define DIM 128
#define LN_EPS 1e-10f

#define ROWS_PER_BUCKET 64
#define N_BUCKETS 782            // ceil(50000/64)
#define BUCKET_CAP 2560          // mean 2048, +11 sigma
#define SB 256                   // scatter blocks (minimize fixed bucket-table cost)
#define EPB 6250                 // edges per scatter block (256*6250 = 1.6M exact)
#define CONVB 256                // convert blocks fused into scatter grid
#define CAPR 76                  // per-row agg list slots (mean 32, +11 sigma)

__device__ __forceinline__ uint f2bf(float x) {
    uint u = __float_as_uint(x);
    return (u + 0x7FFFu + ((u >> 16) & 1u)) >> 16;   // RNE to bf16
}

// ---------------------------------------------------------------------------
// scatter (R21): direct-write — NO LDS edge staging.  Phase A's histogram
// atomicAdd return value (rank) + phase B's reservation (gbase) give the
// final perm slot directly: perm[gbase[b]+rank].  R18/R20's stash+stageE
// (75 KB LDS, 2 extra barriers, 2 full-edge LDS round-trips) existed only to
// coalesce perm writes; scattered 8B writes are L2/byte-mask absorbed and
// cheaper than the staging they replace.  LDS = 6.3 KB -> the whole grid
// (256 scatter + 256 convert blocks x 1024 thr = 8192 waves) is co-resident,
// so the feat/W bf16 convert runs fully concurrent with scatter's
// latency-bound phases.  rank/row stash lives in registers (7 static slots).
// ---------------------------------------------------------------------------
__global__ __launch_bounds__(1024) void scatter(
    const float* __restrict__ feat, const float* __restrict__ W,
    const int* __restrict__ rows, const int* __restrict__ cols,
    const float* __restrict__ vals, int* __restrict__ gcnt,
    int2* __restrict__ perm, uint* __restrict__ featb_u,
    ushort* __restrict__ wbf)
{
    __shared__ int cnt[N_BUCKETS];
    __shared__ int gbase[N_BUCKETS];
    const int bx = blockIdx.x;
    const int t  = threadIdx.x;

    if (bx < CONVB) {                    // ---- fused convert (no LDS use) ----
        const int stride = CONVB * 1024;
        for (int i = bx * 1024 + t; i < N_NODES * DIM / 4; i += stride) {
            float4 v = ((const float4*)feat)[i];
            ((uint2*)featb_u)[i] = make_uint2(
                f2bf(v.x) | (f2bf(v.y) << 16),
                f2bf(v.z) | (f2bf(v.w) << 16));
        }
        for (int i = bx * 1024 + t; i < DIM * DIM / 4; i += stride) {
            float4 v = ((const float4*)W)[i];
            ushort4 o;
            o.x = (ushort)f2bf(v.x); o.y = (ushort)f2bf(v.y);
            o.z = (ushort)f2bf(v.z); o.w = (ushort)f2bf(v.w);
            ((ushort4*)wbf)[i] = o;
        }
        return;
    }
    const int sb   = bx - CONVB;
    const int base = sb * EPB;

    // ---- phase A: histogram; rank + row stashed in registers ----
    for (int i = t; i < N_BUCKETS; i += 1024) cnt[i] = 0;
    __syncthreads();
    int rankv[7], rowv[7];
    #pragma unroll
    for (int i = 0; i < 7; ++i) {
        int k = i * 1024 + t;                  // EPB = 6*1024 + 106
        if (k < EPB) {
            int r = rows[base + k];
            rowv[i]  = r;
            rankv[i] = atomicAdd(&cnt[r >> 6], 1);
        }
    }
    __syncthreads();

    // ---- phase B: global reservation (one atomic per non-empty bucket) ----
    for (int i = t; i < N_BUCKETS; i += 1024) {
        int c = cnt[i];
        gbase[i] = c ? atomicAdd(&gcnt[i], c) : 0;
    }
    __syncthreads();

    // ---- phase C: direct write to final slot ----
    #pragma unroll
    for (int i = 0; i < 7; ++i) {
        int k = i * 1024 + t;
        if (k < EPB) {
            int r = rowv[i], b = r >> 6;
            int pos = gbase[b] + rankv[i];
            if (pos < BUCKET_CAP)           // statistically impossible; safety
                perm[(size_t)b * BUCKET_CAP + pos] = make_int2(
                    (uint)cols[base + k] | ((uint)(r & 63) << 16),
                    __float_as_int(vals[base + k]));
        }
    }
}

// ---------------------------------------------------------------------------
// agg_fused (R21): one block per FULL bucket (782 x 1024 thr, 16 waves,
// 64 rows).  vs R20's half-bucket blocks: perm is read ONCE (half-blocks
// each read the whole list and discarded half -> 2x perm fetch + 2x P1 scan),
// and LDS 39 KB x 2 blocks/CU hits the 32-wave occupancy cap exactly.
// P1 stores the BYTE offset (col<<8) so P2's gather address is one v_add_u32.
// P2: 4 rows/wave, bf16 gathers (lane holds feat elems 2*lane, 2*lane+1).
// P3: rows -> LDS bf16 stride 136, packed uint at word `lane` (true order).
// P4: 64x128 linear via MFMA 16x16x32 bf16 (16 waves x 2 M-tiles, 4 K-steps).
// P5: C+bias -> LDS, ReLU + LN + scale/offset -> out (4 rows/wave).
// ---------------------------------------------------------------------------
__global__ __launch_bounds__(1024, 8) void agg_fused(
    const int2* __restrict__ perm, const int* __restrict__ gcnt,
    const ushort* __restrict__ featb, const ushort* __restrict__ wbf,
    const float* __restrict__ bias, const float* __restrict__ scale,
    const float* __restrict__ offset, float* __restrict__ out)
{
    __shared__ int2 lists[64 * CAPR];    // 38912 B union:
    ushort* rowsbuf = (ushort*)lists;    //   P3/P4: 64 x 136 bf16 (17408 B)
    float*  Cbuf    = (float*)lists;     //   P5:    64 x 132 fp32 (33792 B)
    __shared__ int  lcnt[64];

    const int t = threadIdx.x;
    const int b = blockIdx.x;

    if (t < 64) lcnt[t] = 0;
    __syncthreads();

    int n = gcnt[b];
    if (n > BUCKET_CAP) n = BUCKET_CAP;
    const int2* pb = perm + (size_t)b * BUCKET_CAP;

    // ---- P1: compaction (store byte offset col<<8 for cheap P2 addr) ----
    for (int e = t; e < n; e += 1024) {
        int2 p = pb[e];
        int rl = (p.x >> 16) & 63;
        int pos = atomicAdd(&lcnt[rl], 1);
        if (pos < CAPR)
            lists[rl * CAPR + pos] = make_int2((p.x & 0xFFFF) << 8, p.y);
    }
    __syncthreads();

    const int lane = t & 63;
    const int wid  = t >> 6;        // 0..15
    const int rb   = wid * 4;       // this wave's first local row (0..60)
    const char* fbase = (const char*)featb;
    const uint  lane4 = (uint)lane << 2;

    // ---- P2: gather + accumulate (ax = elem 2*lane, ay = elem 2*lane+1) ----
    float ax[4], ay[4];
    #pragma unroll
    for (int j = 0; j < 4; ++j) {
        int rl = rb + j;
        int cnt = lcnt[rl];
        if (cnt > CAPR) cnt = CAPR;
        const int2* L = &lists[rl * CAPR];
        float sx = 0.f, sy = 0.f;
        int e = 0;
        for (; e + 7 < cnt; e += 8) {
            int2 p[8]; uint g[8];
            #pragma unroll
            for (int k = 0; k < 8; ++k) p[k] = L[e + k];
            #pragma unroll
            for (int k = 0; k < 8; ++k)
                g[k] = *(const uint*)(fbase + ((uint)p[k].x + lane4));
            #pragma unroll
            for (int k = 0; k < 8; ++k) {
                float v = __int_as_float(p[k].y);
                sx = fmaf(v, __uint_as_float(g[k] << 16), sx);
                sy = fmaf(v, __uint_as_float(g[k] & 0xFFFF0000u), sy);
            }
        }
        for (; e < cnt; ++e) {
            int2 p = L[e];
            uint g = *(const uint*)(fbase + ((uint)p.x + lane4));
            float v = __int_as_float(p.y);
            sx = fmaf(v, __uint_as_float(g << 16), sx);
            sy = fmaf(v, __uint_as_float(g & 0xFFFF0000u), sy);
        }
        ax[j] = sx; ay[j] = sy;
    }
    __syncthreads();               // lists dead

    // ---- P3: rows -> LDS bf16 (true element order), stride 136 ushorts ----
    #pragma unroll
    for (int j = 0; j < 4; ++j) {
        uint pk = f2bf(ax[j]) | (f2bf(ay[j]) << 16);
        *(uint*)&rowsbuf[(rb + j) * 136 + 2 * lane] = pk;
    }
    __syncthreads();

    // ---- P4: MFMA GEMM.  D[m][n] = sum_k A[m][k] * W[n][k] ----
    const int l15  = lane & 15;
    const int quad = lane >> 4;
    const int n0   = (wid & 7) * 16 + l15;   // this wave's N-column
    const int m0   = (wid >> 3) * 32;        // this wave's M-base (0 or 32)
    const float bb = bias[n0];

    floatx4 acc0 = {0.f, 0.f, 0.f, 0.f};   // rows m0 .. m0+15
    floatx4 acc1 = {0.f, 0.f, 0.f, 0.f};   // rows m0+16 .. m0+31
    #pragma unroll
    for (int kt = 0; kt < 4; ++kt) {
        int k0 = kt * 32 + quad * 8;
        short8 af0 = *(const short8*)&rowsbuf[(m0 + l15) * 136 + k0];
        short8 af1 = *(const short8*)&rowsbuf[(m0 + l15 + 16) * 136 + k0];
        short8 bf  = *(const short8*)&wbf[n0 * DIM + k0];   // B[k][n]=W[n][k]
        acc0 = __builtin_amdgcn_mfma_f32_16x16x32_bf16(af0, bf, acc0, 0, 0, 0);
        acc1 = __builtin_amdgcn_mfma_f32_16x16x32_bf16(af1, bf, acc1, 0, 0, 0);
    }
    __syncthreads();               // rowsbuf dead

    // C/D layout: lane holds D[m=quad*4+r][n=l15] -> stage to Cbuf (+bias)
    #pragma unroll
    for (int r = 0; r < 4; ++r) {
        int m = m0 + quad * 4 + r;
        Cbuf[m * 132 + n0]        = acc0[r] + bb;
        Cbuf[(m + 16) * 132 + n0] = acc1[r] + bb;
    }
    __syncthreads();

    // ---- P5: ReLU + LN + scale/offset -> out (4 rows per wave) ----
    const float sc0 = scale[lane],  sc1 = scale[lane + 64];
    const float of0 = offset[lane], of1 = offset[lane + 64];

    #pragma unroll
    for (int j = 0; j < 4; ++j) {
        int rl = rb + j;
        int r  = b * ROWS_PER_BUCKET + rl;
        if (r >= N_NODES) continue;                       // wave-uniform
        float A0 = fmaxf(Cbuf[rl * 132 + lane],      0.0f);
        float A1 = fmaxf(Cbuf[rl * 132 + lane + 64], 0.0f);

        float s = A0 + A1;
        #pragma unroll
        for (int off = 32; off >= 1; off >>= 1) s += __shfl_xor(s, off, 64);
        float mean = s * (1.0f / 128.0f);

        float d0 = A0 - mean, d1 = A1 - mean;
        float q2 = d0 * d0 + d1 * d1;
        #pragma unroll
        for (int off = 32; off >= 1; off >>= 1) q2 += __shfl_xor(q2, off, 64);
        float rstd = rsqrtf(q2 * (1.0f / 128.0f) + LN_EPS);

        size_t rowp = (size_t)r * DIM;
        out[rowp + lane]      = d0 * sc0 * rstd + of0;
        out[rowp + lane + 64] = d1 * sc1 * rstd + of1;
    }
}

extern "C" void kernel_launch(void* const* d_in, const int* in_sizes, int n_in,
                              void* d_out, int out_size, void* d_ws, size_t ws_size,
                              hipStream_t stream) {
    const float* feat_in = (const float*)d_in[0];
    const int*   rows    = (const int*)d_in[1];
    const int*   cols    = (const int*)d_in[2];
    const float* vals    = (const float*)d_in[3];
    const float* W       = (const float*)d_in[4];
    const float* bias    = (const float*)d_in[5];
    const float* scale   = (const float*)d_in[6];
    const float* offset  = (const float*)d_in[7];
    float* out = (float*)d_out;

    // ---- workspace layout ----
    char* p = (char*)d_ws;
    int2* perm = (int2*)p;                 p += (size_t)N_BUCKETS * BUCKET_CAP * 8; // 16.0 MB
    ushort* featb = (ushort*)p;            p += (size_t)N_NODES * DIM * 2;          // 12.8 MB
    ushort* wbf = (ushort*)p;              p += DIM * DIM * 2;                      // 32 KB
    int*  gcnt = (int*)p;                  p += (size_t)(N_BUCKETS + 64) * 4;       // 3.4 KB

    hipMemsetAsync(gcnt, 0, (size_t)N_BUCKETS * sizeof(int), stream);

    scatter<<<CONVB + SB, 1024, 0, stream>>>(feat_in, W, rows, cols, vals,
                                             gcnt, perm, (uint*)featb, wbf);
    agg_fused<<<N_BUCKETS, 1024, 0, stream>>>(perm, gcnt, featb, wbf,
                                              bias, scale, offset, out);
}

// Round 4
// 174.909 us; speedup vs baseline: 1.0898x; 1.0898x over previous
//
#include <hip/hip_runtime.h>

typedef unsigned int uint;
typedef unsigned short ushort;
typedef __attribute__((ext_vector_type(8))) short short8;   // 8 bf16 = 4 VGPRs
typedef __attribute__((ext_vector_type(4))) float floatx4;  // MFMA C/D

#define N_NODES 50000
#define N_EDGES 1600000
#define DIM 128
#define LN_EPS 1e-10f

#define NB2 1564                 // half-buckets of 32 rows: ceil(50000/32)
#define CAP2 1280                // mean 1024, +8 sigma
#define EPB 6250                 // edges per scatter block (256*6250 = 1.6M exact)
#define SB 256                   // scatter blocks: one per CU
#define FCB 1563                 // feat-convert blocks (1024 thr, 1 float4 each)
#define CAPR 76                  // per-row agg list slots (mean 32, +7.8 sigma)

__device__ __forceinline__ uint f2bf(float x) {
    uint u = __float_as_uint(x);
    return (u + 0x7FFFu + ((u >> 16) & 1u)) >> 16;   // RNE to bf16
}

// ---------------------------------------------------------------------------
// prep (R22 = R18 staged-clustered scatter, restored after R20/R21 regressions
// (+6/+12us): the LDS stage exists to cluster perm writes into full-line
// write-backs; direct random 8B writes scatter dirty partial lines.  ONE
// change vs R18: bins are HALF-buckets (b' = r>>5, 1564 bins, CAP 1280) so
// each agg block later reads only edges it uses (chip perm read 25.6->12.8MB,
// agg P1 scan halved).  LDS 94 KB -> 1 block/CU (as R18).
// Phase A histogram atomicAdd return value = edge's rank within its bin;
// phase C places at lbase[b]+rank (no second LDS atomic).
// ---------------------------------------------------------------------------
__global__ __launch_bounds__(1024) void prep(
    const float* __restrict__ feat, const float* __restrict__ W,
    const int* __restrict__ rows, const int* __restrict__ cols,
    const float* __restrict__ vals, int* __restrict__ gcnt,
    int2* __restrict__ perm, uint* __restrict__ featb_u,
    ushort* __restrict__ wbf)
{
    __shared__ int  cnt[NB2];
    __shared__ int  gbase[NB2];
    __shared__ int  lbase[NB2];
    __shared__ int  csum[64];
    __shared__ uint stash[EPB];         // 25 KB: (rank<<16) | row
    __shared__ int2 stageE[EPB];        // 50 KB
    const int bx = blockIdx.x;
    const int t  = threadIdx.x;

    if (bx >= SB) {
        int cb = bx - SB;
        if (cb < FCB) {                 // feat fp32 -> packed bf16
            int i = cb * 1024 + t;
            if (i < N_NODES * DIM / 4) {
                float4 v = ((const float4*)feat)[i];
                ((uint2*)featb_u)[i] = make_uint2(
                    f2bf(v.x) | (f2bf(v.y) << 16),
                    f2bf(v.z) | (f2bf(v.w) << 16));
            }
        } else {                        // W -> bf16 row-major (one block)
            for (int idx = t; idx < DIM * DIM; idx += 1024)
                wbf[idx] = (ushort)f2bf(W[idx]);
        }
        return;
    }

    // ---- phase A: rows -> rank-within-bin (histogram's return value) ----
    for (int i = t; i < NB2; i += 1024) cnt[i] = 0;
    __syncthreads();
    const int base = bx * EPB;
    for (int k = t; k < EPB; k += 1024) {
        int r = rows[base + k];
        int rank = atomicAdd(&cnt[r >> 5], 1);   // rank < 6250 (fits 16 bits)
        stash[k] = ((uint)rank << 16) | (uint)r; // r < 50000 (16 bits)
    }
    __syncthreads();

    // ---- phase B: global reservation + LDS exclusive scan (64x25) ----
    for (int i = t; i < NB2; i += 1024) {
        int c = cnt[i];
        gbase[i] = c ? atomicAdd(&gcnt[i], c) : 0;
    }
    if (t < 64) {
        int s = 0;
        for (int j = 0; j < 25; ++j) {
            int idx = t * 25 + j;
            if (idx < NB2) s += cnt[idx];
        }
        csum[t] = s;
    }
    __syncthreads();
    if (t == 0) {
        int s = 0;
        for (int i = 0; i < 64; ++i) { int c = csum[i]; csum[i] = s; s += c; }
    }
    __syncthreads();
    if (t < 64) {
        int run = csum[t];
        for (int j = 0; j < 25; ++j) {
            int idx = t * 25 + j;
            if (idx < NB2) { lbase[idx] = run; run += cnt[idx]; }
        }
    }
    __syncthreads();

    // ---- phase C: stage grouped by bin -- atomic-free placement ----
    // pack: col (16b) | local row r&31 (5b, bits 16-20) | bin (11b, bits 21-31)
    for (int k = t; k < EPB; k += 1024) {
        int e = base + k;
        uint s = stash[k];
        int r = (int)(s & 0xFFFFu);
        int rank = (int)(s >> 16);
        int b = r >> 5;
        int pos = lbase[b] + rank;
        stageE[pos] = make_int2(
            (uint)cols[e] | ((uint)(r & 31) << 16) | ((uint)b << 21),
            __float_as_int(vals[e]));
    }
    __syncthreads();

    // ---- phase D: clustered flush (slot order == destination order) ----
    for (int j = t; j < EPB; j += 1024) {
        int2 p = stageE[j];
        uint b = ((uint)p.x) >> 21;
        int pos = gbase[b] + (j - lbase[b]);
        if (pos < CAP2)                 // statistically impossible; safety
            perm[(size_t)b * CAP2 + pos] = p;       // agg masks b bits
    }
}

// ---------------------------------------------------------------------------
// agg_fused (R22 = R20's best-measured 512-thr structure; full-bucket R21
// reverted).  Changes: reads its OWN half-bucket bin (every fetched edge
// useful -- P1 scan and perm fetch halved), and min-waves 8/EU for 4
// blocks/CU (VGPR 28 << 64-reg bound).
// P1 stores the BYTE offset (col<<8) so P2's gather address is one v_add_u32.
// P2: 4 rows/wave, bf16 gathers (lane holds feat elems 2*lane, 2*lane+1).
// P3: rows -> LDS bf16 stride 136, packed uint at word `lane` (true order).
// P4: 32x128 linear via MFMA 16x16x32 bf16 (8 waves x 2 M-tiles x 4 K-steps).
// P5: C+bias -> LDS, ReLU + LN + scale/offset -> out (4 rows/wave).
// ---------------------------------------------------------------------------
__global__ __launch_bounds__(512, 8) void agg_fused(
    const int2* __restrict__ perm, const int* __restrict__ gcnt,
    const ushort* __restrict__ featb, const ushort* __restrict__ wbf,
    const float* __restrict__ bias, const float* __restrict__ scale,
    const float* __restrict__ offset, float* __restrict__ out)
{
    __shared__ int2 lists[32 * CAPR];    // 19456 B union:
    ushort* rowsbuf = (ushort*)lists;    //   P3/P4: 32 x 136 bf16 (8704 B)
    float*  Cbuf    = (float*)lists;     //   P5:    32 x 132 fp32 (16896 B)
    __shared__ int  lcnt[32];

    const int t = threadIdx.x;

    // bijective XCD-chunked swizzle: each XCD gets a contiguous bin range
    // (neighboring bins share out/featb locality).
    const int q = NB2 >> 3, rr = NB2 & 7;
    const int xcd = blockIdx.x & 7, within = blockIdx.x >> 3;
    const int hb = (xcd < rr ? xcd * (q + 1) : rr * (q + 1) + (xcd - rr) * q) + within;

    if (t < 32) lcnt[t] = 0;
    __syncthreads();

    int n = gcnt[hb];
    if (n > CAP2) n = CAP2;
    const int2* pb = perm + (size_t)hb * CAP2;

    // ---- P1: compaction (store byte offset col<<8 for cheap P2 addr) ----
    for (int e = t; e < n; e += 512) {
        int2 p = pb[e];
        int rl = (p.x >> 16) & 31;
        int pos = atomicAdd(&lcnt[rl], 1);
        if (pos < CAPR)
            lists[rl * CAPR + pos] = make_int2((p.x & 0xFFFF) << 8, p.y);
    }
    __syncthreads();

    const int lane = t & 63;
    const int wid  = t >> 6;        // 0..7
    const int rb   = wid * 4;       // this wave's first local row
    const char* fbase = (const char*)featb;
    const uint  lane4 = (uint)lane << 2;

    // ---- P2: gather + accumulate (ax = elem 2*lane, ay = elem 2*lane+1) ----
    float ax[4], ay[4];
    #pragma unroll
    for (int j = 0; j < 4; ++j) {
        int rl = rb + j;
        int cnt = lcnt[rl];
        if (cnt > CAPR) cnt = CAPR;
        const int2* L = &lists[rl * CAPR];
        float sx = 0.f, sy = 0.f;
        int e = 0;
        for (; e + 7 < cnt; e += 8) {
            int2 p[8]; uint g[8];
            #pragma unroll
            for (int k = 0; k < 8; ++k) p[k] = L[e + k];
            #pragma unroll
            for (int k = 0; k < 8; ++k)
                g[k] = *(const uint*)(fbase + ((uint)p[k].x + lane4));
            #pragma unroll
            for (int k = 0; k < 8; ++k) {
                float v = __int_as_float(p[k].y);
                sx = fmaf(v, __uint_as_float(g[k] << 16), sx);
                sy = fmaf(v, __uint_as_float(g[k] & 0xFFFF0000u), sy);
            }
        }
        for (; e < cnt; ++e) {
            int2 p = L[e];
            uint g = *(const uint*)(fbase + ((uint)p.x + lane4));
            float v = __int_as_float(p.y);
            sx = fmaf(v, __uint_as_float(g << 16), sx);
            sy = fmaf(v, __uint_as_float(g & 0xFFFF0000u), sy);
        }
        ax[j] = sx; ay[j] = sy;
    }
    __syncthreads();               // lists dead

    // ---- P3: rows -> LDS bf16 (true element order), stride 136 ushorts ----
    #pragma unroll
    for (int j = 0; j < 4; ++j) {
        uint pk = f2bf(ax[j]) | (f2bf(ay[j]) << 16);
        *(uint*)&rowsbuf[(rb + j) * 136 + 2 * lane] = pk;
    }
    __syncthreads();

    // ---- P4: MFMA GEMM.  D[m][n] = sum_k A[m][k] * W[n][k] ----
    const int l15  = lane & 15;
    const int quad = lane >> 4;
    const int n0   = wid * 16 + l15;       // this wave's N-column
    const float bb = bias[n0];

    floatx4 acc0 = {0.f, 0.f, 0.f, 0.f};   // m-tile 0 (rows 0..15)
    floatx4 acc1 = {0.f, 0.f, 0.f, 0.f};   // m-tile 1 (rows 16..31)
    #pragma unroll
    for (int kt = 0; kt < 4; ++kt) {
        int k0 = kt * 32 + quad * 8;
        short8 af0 = *(const short8*)&rowsbuf[l15 * 136 + k0];
        short8 af1 = *(const short8*)&rowsbuf[(l15 + 16) * 136 + k0];
        short8 bf  = *(const short8*)&wbf[n0 * DIM + k0];   // B[k][n]=W[n][k]
        acc0 = __builtin_amdgcn_mfma_f32_16x16x32_bf16(af0, bf, acc0, 0, 0, 0);
        acc1 = __builtin_amdgcn_mfma_f32_16x16x32_bf16(af1, bf, acc1, 0, 0, 0);
    }
    __syncthreads();               // rowsbuf dead

    // C/D layout: lane holds D[m=quad*4+r][n=l15] -> stage to Cbuf (+bias)
    #pragma unroll
    for (int r = 0; r < 4; ++r) {
        int m = quad * 4 + r;
        Cbuf[m * 132 + n0]        = acc0[r] + bb;
        Cbuf[(m + 16) * 132 + n0] = acc1[r] + bb;
    }
    __syncthreads();

    // ---- P5: ReLU + LN + scale/offset -> out (4 rows per wave) ----
    const float sc0 = scale[lane],  sc1 = scale[lane + 64];
    const float of0 = offset[lane], of1 = offset[lane + 64];

    #pragma unroll
    for (int j = 0; j < 4; ++j) {
        int rl = rb + j;
        int r  = hb * 32 + rl;
        if (r >= N_NODES) continue;                       // wave-uniform
        float A0 = fmaxf(Cbuf[rl * 132 + lane],      0.0f);
        float A1 = fmaxf(Cbuf[rl * 132 + lane + 64], 0.0f);

        float s = A0 + A1;
        #pragma unroll
        for (int off = 32; off >= 1; off >>= 1) s += __shfl_xor(s, off, 64);
        float mean = s * (1.0f / 128.0f);

        float d0 = A0 - mean, d1 = A1 - mean;
        float q2 = d0 * d0 + d1 * d1;
        #pragma unroll
        for (int off = 32; off >= 1; off >>= 1) q2 += __shfl_xor(q2, off, 64);
        float rstd = rsqrtf(q2 * (1.0f / 128.0f) + LN_EPS);

        size_t rowp = (size_t)r * DIM;
        out[rowp + lane]      = d0 * sc0 * rstd + of0;
        out[rowp + lane + 64] = d1 * sc1 * rstd + of1;
    }
}

extern "C" void kernel_launch(void* const* d_in, const int* in_sizes, int n_in,
                              void* d_out, int out_size, void* d_ws, size_t ws_size,
                              hipStream_t stream) {
    const float* feat_in = (const float*)d_in[0];
    const int*   rows    = (const int*)d_in[1];
    const int*   cols    = (const int*)d_in[2];
    const float* vals    = (const float*)d_in[3];
    const float* W       = (const float*)d_in[4];
    const float* bias    = (const float*)d_in[5];
    const float* scale   = (const float*)d_in[6];
    const float* offset  = (const float*)d_in[7];
    float* out = (float*)d_out;

    // ---- workspace layout ----
    char* p = (char*)d_ws;
    int2* perm = (int2*)p;                 p += (size_t)NB2 * CAP2 * 8;        // 16.0 MB
    ushort* featb = (ushort*)p;            p += (size_t)N_NODES * DIM * 2;     // 12.8 MB
    ushort* wbf = (ushort*)p;              p += DIM * DIM * 2;                 // 32 KB
    int*  gcnt = (int*)p;                  p += (size_t)(NB2 + 64) * 4;        // 6.4 KB

    hipMemsetAsync(gcnt, 0, (size_t)NB2 * sizeof(int), stream);

    prep<<<SB + FCB + 1, 1024, 0, stream>>>(feat_in, W, rows, cols, vals,
                                            gcnt, perm, (uint*)featb, wbf);
    agg_fused<<<NB2, 512, 0, stream>>>(perm, gcnt, featb, wbf,
                                       bias, scale, offset, out);
}

// Round 5
// 174.893 us; speedup vs baseline: 1.0899x; 1.0001x over previous
//
#include <hip/hip_runtime.h>

typedef unsigned int uint;
typedef unsigned short ushort;
typedef __attribute__((ext_vector_type(8))) short short8;   // 8 bf16 = 4 VGPRs
typedef __attribute__((ext_vector_type(4))) float floatx4;  // MFMA C/D

#define N_NODES 50000
#define N_EDGES 1600000
#define DIM 128
#define LN_EPS 1e-10f

#define NB2 1564                 // half-buckets of 32 rows: ceil(50000/32)
#define CAP2 1280                // mean 1024, +8 sigma
#define EPB 6250                 // edges per scatter block (256*6250 = 1.6M exact)
#define SB 256                   // scatter blocks: one per CU
#define CAPR 76                  // per-row agg list slots (mean 32, +7.8 sigma)

__device__ __forceinline__ uint f2bf(float x) {
    uint u = __float_as_uint(x);
    return (u + 0x7FFFu + ((u >> 16) & 1u)) >> 16;   // RNE to bf16
}

// ---------------------------------------------------------------------------
// setup (R23): replaces the hipMemsetAsync dispatch.  Zeroes gcnt AND does
// the feat/W bf16 convert with ZERO LDS at full occupancy.  R18/R22 ran the
// convert as 1563 blocks inside the 94-KB-LDS scatter kernel -> 1 block/CU,
// ~6 serialized rounds of trivial work.  Here it is pure streaming (~38 MB).
// ---------------------------------------------------------------------------
__global__ __launch_bounds__(256) void setup(
    const float* __restrict__ feat, const float* __restrict__ W,
    uint* __restrict__ featb_u, ushort* __restrict__ wbf,
    int* __restrict__ gcnt)
{
    const int stride = gridDim.x * 256;
    if (blockIdx.x == 0)
        for (int i = threadIdx.x; i < NB2; i += 256) gcnt[i] = 0;
    for (int i = blockIdx.x * 256 + threadIdx.x; i < N_NODES * DIM / 4; i += stride) {
        float4 v = ((const float4*)feat)[i];
        ((uint2*)featb_u)[i] = make_uint2(
            f2bf(v.x) | (f2bf(v.y) << 16),
            f2bf(v.z) | (f2bf(v.w) << 16));
    }
    for (int i = blockIdx.x * 256 + threadIdx.x; i < DIM * DIM / 4; i += stride) {
        float4 v = ((const float4*)W)[i];
        ushort4 o;
        o.x = (ushort)f2bf(v.x); o.y = (ushort)f2bf(v.y);
        o.z = (ushort)f2bf(v.z); o.w = (ushort)f2bf(v.w);
        ((ushort4*)wbf)[i] = o;
    }
}

// ---------------------------------------------------------------------------
// scatter (R23): pure staged-clustered scatter (the measured-best R18/R22
// write path) with the 25 KB LDS stash replaced by a 7-slot REGISTER stash
// (rank<<16 | row), proven in R21.  One less full-edge LDS round-trip;
// LDS 94 -> 69 KB.  Bins are half-buckets (r>>5, 1564 bins, CAP 1280).
// Phase A histogram atomicAdd return value = edge's rank within its bin;
// phase C places at lbase[b]+rank (no second LDS atomic); phase D flushes
// in slot order == destination order (full-line clustered perm writes).
// ---------------------------------------------------------------------------
__global__ __launch_bounds__(1024) void scatter(
    const int* __restrict__ rows, const int* __restrict__ cols,
    const float* __restrict__ vals, int* __restrict__ gcnt,
    int2* __restrict__ perm)
{
    __shared__ int  cnt[NB2];
    __shared__ int  gbase[NB2];
    __shared__ int  lbase[NB2];
    __shared__ int  csum[64];
    __shared__ int2 stageE[EPB];        // 50 KB
    const int bx = blockIdx.x;
    const int t  = threadIdx.x;

    // ---- phase A: rows -> rank-within-bin, stashed in registers ----
    for (int i = t; i < NB2; i += 1024) cnt[i] = 0;
    __syncthreads();
    const int base = bx * EPB;
    uint pk[7];                          // EPB = 6*1024 + 106
    #pragma unroll
    for (int i = 0; i < 7; ++i) {
        int k = i * 1024 + t;
        if (k < EPB) {
            int r = rows[base + k];
            int rank = atomicAdd(&cnt[r >> 5], 1);  // rank < 6250 (13 bits)
            pk[i] = ((uint)rank << 16) | (uint)r;   // r < 50000 (16 bits)
        }
    }
    __syncthreads();

    // ---- phase B: global reservation + LDS exclusive scan (64x25) ----
    for (int i = t; i < NB2; i += 1024) {
        int c = cnt[i];
        gbase[i] = c ? atomicAdd(&gcnt[i], c) : 0;
    }
    if (t < 64) {
        int s = 0;
        for (int j = 0; j < 25; ++j) {
            int idx = t * 25 + j;
            if (idx < NB2) s += cnt[idx];
        }
        csum[t] = s;
    }
    __syncthreads();
    if (t == 0) {
        int s = 0;
        for (int i = 0; i < 64; ++i) { int c = csum[i]; csum[i] = s; s += c; }
    }
    __syncthreads();
    if (t < 64) {
        int run = csum[t];
        for (int j = 0; j < 25; ++j) {
            int idx = t * 25 + j;
            if (idx < NB2) { lbase[idx] = run; run += cnt[idx]; }
        }
    }
    __syncthreads();

    // ---- phase C: stage grouped by bin -- atomic-free placement ----
    // pack: col (16b) | local row r&31 (5b, bits 16-20) | bin (11b, bits 21-31)
    #pragma unroll
    for (int i = 0; i < 7; ++i) {
        int k = i * 1024 + t;
        if (k < EPB) {
            uint s = pk[i];
            int r = (int)(s & 0xFFFFu);
            int rank = (int)(s >> 16);
            int b = r >> 5;
            int pos = lbase[b] + rank;
            stageE[pos] = make_int2(
                (uint)cols[base + k] | ((uint)(r & 31) << 16) | ((uint)b << 21),
                __float_as_int(vals[base + k]));
        }
    }
    __syncthreads();

    // ---- phase D: clustered flush (slot order == destination order) ----
    for (int j = t; j < EPB; j += 1024) {
        int2 p = stageE[j];
        uint b = ((uint)p.x) >> 21;
        int pos = gbase[b] + (j - lbase[b]);
        if (pos < CAP2)                 // statistically impossible; safety
            perm[(size_t)b * CAP2 + pos] = p;       // agg masks b bits
    }
}

// ---------------------------------------------------------------------------
// agg_fused (R23 = R22 structure; one change: P2 gather pipeline deepened
// 8 -> 12 outstanding loads/lane, with list entries read as paired int4
// (ds_read_b128, half the LDS ops).  VALUBusy 32% / Occ 62% said latency-
// bound; this is the MLP test.  VGPR predicted ~60 (<= 64 for 8 waves/SIMD).
// P1 stores the BYTE offset (col<<8) so P2's gather address is one v_add_u32.
// P2: 4 rows/wave, bf16 gathers (lane holds feat elems 2*lane, 2*lane+1).
// P3: rows -> LDS bf16 stride 136, packed uint at word `lane` (true order).
// P4: 32x128 linear via MFMA 16x16x32 bf16 (8 waves x 2 M-tiles x 4 K-steps).
// P5: C+bias -> LDS, ReLU + LN + scale/offset -> out (4 rows/wave).
// ---------------------------------------------------------------------------
__global__ __launch_bounds__(512, 8) void agg_fused(
    const int2* __restrict__ perm, const int* __restrict__ gcnt,
    const ushort* __restrict__ featb, const ushort* __restrict__ wbf,
    const float* __restrict__ bias, const float* __restrict__ scale,
    const float* __restrict__ offset, float* __restrict__ out)
{
    __shared__ int2 lists[32 * CAPR];    // 19456 B union:
    ushort* rowsbuf = (ushort*)lists;    //   P3/P4: 32 x 136 bf16 (8704 B)
    float*  Cbuf    = (float*)lists;     //   P5:    32 x 132 fp32 (16896 B)
    __shared__ int  lcnt[32];

    const int t = threadIdx.x;

    // bijective XCD-chunked swizzle: each XCD gets a contiguous bin range
    const int q = NB2 >> 3, rr = NB2 & 7;
    const int xcd = blockIdx.x & 7, within = blockIdx.x >> 3;
    const int hb = (xcd < rr ? xcd * (q + 1) : rr * (q + 1) + (xcd - rr) * q) + within;

    if (t < 32) lcnt[t] = 0;
    __syncthreads();

    int n = gcnt[hb];
    if (n > CAP2) n = CAP2;
    const int2* pb = perm + (size_t)hb * CAP2;

    // ---- P1: compaction (store byte offset col<<8 for cheap P2 addr) ----
    for (int e = t; e < n; e += 512) {
        int2 p = pb[e];
        int rl = (p.x >> 16) & 31;
        int pos = atomicAdd(&lcnt[rl], 1);
        if (pos < CAPR)
            lists[rl * CAPR + pos] = make_int2((p.x & 0xFFFF) << 8, p.y);
    }
    __syncthreads();

    const int lane = t & 63;
    const int wid  = t >> 6;        // 0..7
    const int rb   = wid * 4;       // this wave's first local row
    const char* fbase = (const char*)featb;
    const uint  lane4 = (uint)lane << 2;

    // ---- P2: gather + accumulate (ax = elem 2*lane, ay = elem 2*lane+1) ----
    float ax[4], ay[4];
    #pragma unroll
    for (int j = 0; j < 4; ++j) {
        int rl = rb + j;
        int cnt = lcnt[rl];
        if (cnt > CAPR) cnt = CAPR;
        const int2* L = &lists[rl * CAPR];
        float sx = 0.f, sy = 0.f;
        int e = 0;
        for (; e + 11 < cnt; e += 12) {           // 12 outstanding gathers
            int4 q6[6]; uint g[12];
            #pragma unroll
            for (int k = 0; k < 6; ++k) q6[k] = *(const int4*)&L[e + 2 * k];
            #pragma unroll
            for (int k = 0; k < 6; ++k) {
                g[2*k]   = *(const uint*)(fbase + ((uint)q6[k].x + lane4));
                g[2*k+1] = *(const uint*)(fbase + ((uint)q6[k].z + lane4));
            }
            #pragma unroll
            for (int k = 0; k < 6; ++k) {
                float v0 = __int_as_float(q6[k].y);
                float v1 = __int_as_float(q6[k].w);
                sx = fmaf(v0, __uint_as_float(g[2*k] << 16), sx);
                sy = fmaf(v0, __uint_as_float(g[2*k] & 0xFFFF0000u), sy);
                sx = fmaf(v1, __uint_as_float(g[2*k+1] << 16), sx);
                sy = fmaf(v1, __uint_as_float(g[2*k+1] & 0xFFFF0000u), sy);
            }
        }
        for (; e + 3 < cnt; e += 4) {
            int4 q2[2]; uint g[4];
            #pragma unroll
            for (int k = 0; k < 2; ++k) q2[k] = *(const int4*)&L[e + 2 * k];
            #pragma unroll
            for (int k = 0; k < 2; ++k) {
                g[2*k]   = *(const uint*)(fbase + ((uint)q2[k].x + lane4));
                g[2*k+1] = *(const uint*)(fbase + ((uint)q2[k].z + lane4));
            }
            #pragma unroll
            for (int k = 0; k < 2; ++k) {
                float v0 = __int_as_float(q2[k].y);
                float v1 = __int_as_float(q2[k].w);
                sx = fmaf(v0, __uint_as_float(g[2*k] << 16), sx);
                sy = fmaf(v0, __uint_as_float(g[2*k] & 0xFFFF0000u), sy);
                sx = fmaf(v1, __uint_as_float(g[2*k+1] << 16), sx);
                sy = fmaf(v1, __uint_as_float(g[2*k+1] & 0xFFFF0000u), sy);
            }
        }
        for (; e < cnt; ++e) {
            int2 p = L[e];
            uint g = *(const uint*)(fbase + ((uint)p.x + lane4));
            float v = __int_as_float(p.y);
            sx = fmaf(v, __uint_as_float(g << 16), sx);
            sy = fmaf(v, __uint_as_float(g & 0xFFFF0000u), sy);
        }
        ax[j] = sx; ay[j] = sy;
    }
    __syncthreads();               // lists dead

    // ---- P3: rows -> LDS bf16 (true element order), stride 136 ushorts ----
    #pragma unroll
    for (int j = 0; j < 4; ++j) {
        uint pk = f2bf(ax[j]) | (f2bf(ay[j]) << 16);
        *(uint*)&rowsbuf[(rb + j) * 136 + 2 * lane] = pk;
    }
    __syncthreads();

    // ---- P4: MFMA GEMM.  D[m][n] = sum_k A[m][k] * W[n][k] ----
    const int l15  = lane & 15;
    const int quad = lane >> 4;
    const int n0   = wid * 16 + l15;       // this wave's N-column
    const float bb = bias[n0];

    floatx4 acc0 = {0.f, 0.f, 0.f, 0.f};   // m-tile 0 (rows 0..15)
    floatx4 acc1 = {0.f, 0.f, 0.f, 0.f};   // m-tile 1 (rows 16..31)
    #pragma unroll
    for (int kt = 0; kt < 4; ++kt) {
        int k0 = kt * 32 + quad * 8;
        short8 af0 = *(const short8*)&rowsbuf[l15 * 136 + k0];
        short8 af1 = *(const short8*)&rowsbuf[(l15 + 16) * 136 + k0];
        short8 bf  = *(const short8*)&wbf[n0 * DIM + k0];   // B[k][n]=W[n][k]
        acc0 = __builtin_amdgcn_mfma_f32_16x16x32_bf16(af0, bf, acc0, 0, 0, 0);
        acc1 = __builtin_amdgcn_mfma_f32_16x16x32_bf16(af1, bf, acc1, 0, 0, 0);
    }
    __syncthreads();               // rowsbuf dead

    // C/D layout: lane holds D[m=quad*4+r][n=l15] -> stage to Cbuf (+bias)
    #pragma unroll
    for (int r = 0; r < 4; ++r) {
        int m = quad * 4 + r;
        Cbuf[m * 132 + n0]        = acc0[r] + bb;
        Cbuf[(m + 16) * 132 + n0] = acc1[r] + bb;
    }
    __syncthreads();

    // ---- P5: ReLU + LN + scale/offset -> out (4 rows per wave) ----
    const float sc0 = scale[lane],  sc1 = scale[lane + 64];
    const float of0 = offset[lane], of1 = offset[lane + 64];

    #pragma unroll
    for (int j = 0; j < 4; ++j) {
        int rl = rb + j;
        int r  = hb * 32 + rl;
        if (r >= N_NODES) continue;                       // wave-uniform
        float A0 = fmaxf(Cbuf[rl * 132 + lane],      0.0f);
        float A1 = fmaxf(Cbuf[rl * 132 + lane + 64], 0.0f);

        float s = A0 + A1;
        #pragma unroll
        for (int off = 32; off >= 1; off >>= 1) s += __shfl_xor(s, off, 64);
        float mean = s * (1.0f / 128.0f);

        float d0 = A0 - mean, d1 = A1 - mean;
        float q2 = d0 * d0 + d1 * d1;
        #pragma unroll
        for (int off = 32; off >= 1; off >>= 1) q2 += __shfl_xor(q2, off, 64);
        float rstd = rsqrtf(q2 * (1.0f / 128.0f) + LN_EPS);

        size_t rowp = (size_t)r * DIM;
        out[rowp + lane]      = d0 * sc0 * rstd + of0;
        out[rowp + lane + 64] = d1 * sc1 * rstd + of1;
    }
}

extern "C" void kernel_launch(void* const* d_in, const int* in_sizes, int n_in,
                              void* d_out, int out_size, void* d_ws, size_t ws_size,
                              hipStream_t stream) {
    const float* feat_in = (const float*)d_in[0];
    const int*   rows    = (const int*)d_in[1];
    const int*   cols    = (const int*)d_in[2];
    const float* vals    = (const float*)d_in[3];
    const float* W       = (const float*)d_in[4];
    const float* bias    = (const float*)d_in[5];
    const float* scale   = (const float*)d_in[6];
    const float* offset  = (const float*)d_in[7];
    float* out = (float*)d_out;

    // ---- workspace layout ----
    char* p = (char*)d_ws;
    int2* perm = (int2*)p;                 p += (size_t)NB2 * CAP2 * 8;        // 16.0 MB
    ushort* featb = (ushort*)p;            p += (size_t)N_NODES * DIM * 2;     // 12.8 MB
    ushort* wbf = (ushort*)p;              p += DIM * DIM * 2;                 // 32 KB
    int*  gcnt = (int*)p;                  p += (size_t)(NB2 + 64) * 4;        // 6.4 KB

    setup<<<1024, 256, 0, stream>>>(feat_in, W, (uint*)featb, wbf, gcnt);
    scatter<<<SB, 1024, 0, stream>>>(rows, cols, vals, gcnt, perm);
    agg_fused<<<NB2, 512, 0, stream>>>(perm, gcnt, featb, wbf,
                                       bias, scale, offset, out);
}

// Round 6
// 170.706 us; speedup vs baseline: 1.1166x; 1.0245x over previous
//
#include <hip/hip_runtime.h>

typedef unsigned int uint;
typedef unsigned short ushort;
typedef __attribute__((ext_vector_type(8))) short short8;   // 8 bf16 = 4 VGPRs
typedef __attribute__((ext_vector_type(4))) float floatx4;  // MFMA C/D

#define N_NODES 50000
#define N_EDGES 1600000
#define DIM 128
#define LN_EPS 1e-10f

#define NB2 1564                 // half-buckets of 32 rows: ceil(50000/32)
#define CAP2 1280                // mean 1024, +8 sigma
#define EPB 6250                 // edges per scatter block (256*6250 = 1.6M exact)
#define SB 256                   // scatter blocks
#define CONVB 256                // grid-stride convert blocks fused into prep
#define CAPR 76                  // per-row agg list slots (mean 32, +7.8 sigma)

__device__ __forceinline__ uint f2bf(float x) {
    uint u = __float_as_uint(x);
    return (u + 0x7FFFu + ((u >> 16) & 1u)) >> 16;   // RNE to bf16
}

// ---------------------------------------------------------------------------
// prep (R24): fused scatter + convert, recombining the measured-best pieces.
// Evidence: fused prep beats split (rest 110.5 R22 vs 114.6 R23) -- convert
// blocks fill CU slots while scatter's latency phases stall, and one less
// dispatch gap.  vs R22: register stash (no 25 KB LDS stash) -> 69 KB LDS ->
// 2 blocks/CU, and convert is 256 GRID-STRIDE blocks, so the whole 512-block
// grid is co-resident in one wave-launch (R22's 1563 one-shot convert blocks
// trickled through at 1 block/CU AFTER scatter).
// Phase B de-contention: blocks previously walked bins 0..1563 in identical
// order -> 256 near-simultaneous same-address atomics per gcnt line.  Rotate
// each block's start by bx*16 bins (64 B) so concurrent atomics hit
// different L2 lines.
// Phase A histogram atomicAdd return value = edge's rank within its bin;
// phase C places at lbase[b]+rank (no second LDS atomic); phase D flushes
// in slot order == destination order (full-line clustered perm writes).
// ---------------------------------------------------------------------------
__global__ __launch_bounds__(1024, 8) void prep(
    const float* __restrict__ feat, const float* __restrict__ W,
    const int* __restrict__ rows, const int* __restrict__ cols,
    const float* __restrict__ vals, int* __restrict__ gcnt,
    int2* __restrict__ perm, uint* __restrict__ featb_u,
    ushort* __restrict__ wbf)
{
    __shared__ int  cnt[NB2];           // 6.3 KB
    __shared__ int  gbase[NB2];         // 6.3 KB
    __shared__ int  lbase[NB2];         // 6.3 KB
    __shared__ int  csum[64];
    __shared__ int2 stageE[EPB];        // 50 KB   (total 69 KB -> 2 blocks/CU)
    const int bx = blockIdx.x;
    const int t  = threadIdx.x;

    if (bx >= SB) {                      // ---- fused convert (no LDS use) ----
        const int cb = bx - SB;
        const int stride = CONVB * 1024;
        for (int i = cb * 1024 + t; i < N_NODES * DIM / 4; i += stride) {
            float4 v = ((const float4*)feat)[i];
            ((uint2*)featb_u)[i] = make_uint2(
                f2bf(v.x) | (f2bf(v.y) << 16),
                f2bf(v.z) | (f2bf(v.w) << 16));
        }
        for (int i = cb * 1024 + t; i < DIM * DIM / 4; i += stride) {
            float4 v = ((const float4*)W)[i];
            ushort4 o;
            o.x = (ushort)f2bf(v.x); o.y = (ushort)f2bf(v.y);
            o.z = (ushort)f2bf(v.z); o.w = (ushort)f2bf(v.w);
            ((ushort4*)wbf)[i] = o;
        }
        return;
    }

    // ---- phase A: rows -> rank-within-bin, stashed in registers ----
    for (int i = t; i < NB2; i += 1024) cnt[i] = 0;
    __syncthreads();
    const int base = bx * EPB;
    uint pk[7];                          // EPB = 6*1024 + 106
    #pragma unroll
    for (int i = 0; i < 7; ++i) {
        int k = i * 1024 + t;
        if (k < EPB) {
            int r = rows[base + k];
            int rank = atomicAdd(&cnt[r >> 5], 1);  // rank < 6250 (13 bits)
            pk[i] = ((uint)rank << 16) | (uint)r;   // r < 50000 (16 bits)
        }
    }
    __syncthreads();

    // ---- phase B: global reservation (line-rotated) + LDS scan (64x25) ----
    {
        const int rot = (bx * 16) % NB2;             // 64 B line offset/block
        for (int i = t; i < NB2; i += 1024) {
            int ii = i + rot; if (ii >= NB2) ii -= NB2;
            int c = cnt[ii];
            gbase[ii] = c ? atomicAdd(&gcnt[ii], c) : 0;
        }
    }
    if (t < 64) {
        int s = 0;
        for (int j = 0; j < 25; ++j) {
            int idx = t * 25 + j;
            if (idx < NB2) s += cnt[idx];
        }
        csum[t] = s;
    }
    __syncthreads();
    if (t == 0) {
        int s = 0;
        for (int i = 0; i < 64; ++i) { int c = csum[i]; csum[i] = s; s += c; }
    }
    __syncthreads();
    if (t < 64) {
        int run = csum[t];
        for (int j = 0; j < 25; ++j) {
            int idx = t * 25 + j;
            if (idx < NB2) { lbase[idx] = run; run += cnt[idx]; }
        }
    }
    __syncthreads();

    // ---- phase C: stage grouped by bin -- atomic-free placement ----
    // pack: col (16b) | local row r&31 (5b, bits 16-20) | bin (11b, bits 21-31)
    #pragma unroll
    for (int i = 0; i < 7; ++i) {
        int k = i * 1024 + t;
        if (k < EPB) {
            uint s = pk[i];
            int r = (int)(s & 0xFFFFu);
            int rank = (int)(s >> 16);
            int b = r >> 5;
            int pos = lbase[b] + rank;
            stageE[pos] = make_int2(
                (uint)cols[base + k] | ((uint)(r & 31) << 16) | ((uint)b << 21),
                __float_as_int(vals[base + k]));
        }
    }
    __syncthreads();

    // ---- phase D: clustered flush (slot order == destination order) ----
    for (int j = t; j < EPB; j += 1024) {
        int2 p = stageE[j];
        uint b = ((uint)p.x) >> 21;
        int pos = gbase[b] + (j - lbase[b]);
        if (pos < CAP2)                 // statistically impossible; safety
            perm[(size_t)b * CAP2 + pos] = p;       // agg masks b bits
    }
}

// ---------------------------------------------------------------------------
// agg_fused (R24 = R23 unchanged; 60.2 us measured, BW 2.93 TB/s at the
// random-256B-gather fabric rate).  P2 runs a 12-deep gather pipeline with
// paired int4 list reads; P1 stores BYTE offsets (col<<8) for 1-add addrs.
// P2: 4 rows/wave, bf16 gathers (lane holds feat elems 2*lane, 2*lane+1).
// P3: rows -> LDS bf16 stride 136, packed uint at word `lane` (true order).
// P4: 32x128 linear via MFMA 16x16x32 bf16 (8 waves x 2 M-tiles x 4 K-steps).
// P5: C+bias -> LDS, ReLU + LN + scale/offset -> out (4 rows/wave).
// ---------------------------------------------------------------------------
__global__ __launch_bounds__(512, 8) void agg_fused(
    const int2* __restrict__ perm, const int* __restrict__ gcnt,
    const ushort* __restrict__ featb, const ushort* __restrict__ wbf,
    const float* __restrict__ bias, const float* __restrict__ scale,
    const float* __restrict__ offset, float* __restrict__ out)
{
    __shared__ int2 lists[32 * CAPR];    // 19456 B union:
    ushort* rowsbuf = (ushort*)lists;    //   P3/P4: 32 x 136 bf16 (8704 B)
    float*  Cbuf    = (float*)lists;     //   P5:    32 x 132 fp32 (16896 B)
    __shared__ int  lcnt[32];

    const int t = threadIdx.x;

    // bijective XCD-chunked swizzle: each XCD gets a contiguous bin range
    const int q = NB2 >> 3, rr = NB2 & 7;
    const int xcd = blockIdx.x & 7, within = blockIdx.x >> 3;
    const int hb = (xcd < rr ? xcd * (q + 1) : rr * (q + 1) + (xcd - rr) * q) + within;

    if (t < 32) lcnt[t] = 0;
    __syncthreads();

    int n = gcnt[hb];
    if (n > CAP2) n = CAP2;
    const int2* pb = perm + (size_t)hb * CAP2;

    // ---- P1: compaction (store byte offset col<<8 for cheap P2 addr) ----
    for (int e = t; e < n; e += 512) {
        int2 p = pb[e];
        int rl = (p.x >> 16) & 31;
        int pos = atomicAdd(&lcnt[rl], 1);
        if (pos < CAPR)
            lists[rl * CAPR + pos] = make_int2((p.x & 0xFFFF) << 8, p.y);
    }
    __syncthreads();

    const int lane = t & 63;
    const int wid  = t >> 6;        // 0..7
    const int rb   = wid * 4;       // this wave's first local row
    const char* fbase = (const char*)featb;
    const uint  lane4 = (uint)lane << 2;

    // ---- P2: gather + accumulate (ax = elem 2*lane, ay = elem 2*lane+1) ----
    float ax[4], ay[4];
    #pragma unroll
    for (int j = 0; j < 4; ++j) {
        int rl = rb + j;
        int cnt = lcnt[rl];
        if (cnt > CAPR) cnt = CAPR;
        const int2* L = &lists[rl * CAPR];
        float sx = 0.f, sy = 0.f;
        int e = 0;
        for (; e + 11 < cnt; e += 12) {           // 12 outstanding gathers
            int4 q6[6]; uint g[12];
            #pragma unroll
            for (int k = 0; k < 6; ++k) q6[k] = *(const int4*)&L[e + 2 * k];
            #pragma unroll
            for (int k = 0; k < 6; ++k) {
                g[2*k]   = *(const uint*)(fbase + ((uint)q6[k].x + lane4));
                g[2*k+1] = *(const uint*)(fbase + ((uint)q6[k].z + lane4));
            }
            #pragma unroll
            for (int k = 0; k < 6; ++k) {
                float v0 = __int_as_float(q6[k].y);
                float v1 = __int_as_float(q6[k].w);
                sx = fmaf(v0, __uint_as_float(g[2*k] << 16), sx);
                sy = fmaf(v0, __uint_as_float(g[2*k] & 0xFFFF0000u), sy);
                sx = fmaf(v1, __uint_as_float(g[2*k+1] << 16), sx);
                sy = fmaf(v1, __uint_as_float(g[2*k+1] & 0xFFFF0000u), sy);
            }
        }
        for (; e + 3 < cnt; e += 4) {
            int4 q2[2]; uint g[4];
            #pragma unroll
            for (int k = 0; k < 2; ++k) q2[k] = *(const int4*)&L[e + 2 * k];
            #pragma unroll
            for (int k = 0; k < 2; ++k) {
                g[2*k]   = *(const uint*)(fbase + ((uint)q2[k].x + lane4));
                g[2*k+1] = *(const uint*)(fbase + ((uint)q2[k].z + lane4));
            }
            #pragma unroll
            for (int k = 0; k < 2; ++k) {
                float v0 = __int_as_float(q2[k].y);
                float v1 = __int_as_float(q2[k].w);
                sx = fmaf(v0, __uint_as_float(g[2*k] << 16), sx);
                sy = fmaf(v0, __uint_as_float(g[2*k] & 0xFFFF0000u), sy);
                sx = fmaf(v1, __uint_as_float(g[2*k+1] << 16), sx);
                sy = fmaf(v1, __uint_as_float(g[2*k+1] & 0xFFFF0000u), sy);
            }
        }
        for (; e < cnt; ++e) {
            int2 p = L[e];
            uint g = *(const uint*)(fbase + ((uint)p.x + lane4));
            float v = __int_as_float(p.y);
            sx = fmaf(v, __uint_as_float(g << 16), sx);
            sy = fmaf(v, __uint_as_float(g & 0xFFFF0000u), sy);
        }
        ax[j] = sx; ay[j] = sy;
    }
    __syncthreads();               // lists dead

    // ---- P3: rows -> LDS bf16 (true element order), stride 136 ushorts ----
    #pragma unroll
    for (int j = 0; j < 4; ++j) {
        uint pk = f2bf(ax[j]) | (f2bf(ay[j]) << 16);
        *(uint*)&rowsbuf[(rb + j) * 136 + 2 * lane] = pk;
    }
    __syncthreads();

    // ---- P4: MFMA GEMM.  D[m][n] = sum_k A[m][k] * W[n][k] ----
    const int l15  = lane & 15;
    const int quad = lane >> 4;
    const int n0   = wid * 16 + l15;       // this wave's N-column
    const float bb = bias[n0];

    floatx4 acc0 = {0.f, 0.f, 0.f, 0.f};   // m-tile 0 (rows 0..15)
    floatx4 acc1 = {0.f, 0.f, 0.f, 0.f};   // m-tile 1 (rows 16..31)
    #pragma unroll
    for (int kt = 0; kt < 4; ++kt) {
        int k0 = kt * 32 + quad * 8;
        short8 af0 = *(const short8*)&rowsbuf[l15 * 136 + k0];
        short8 af1 = *(const short8*)&rowsbuf[(l15 + 16) * 136 + k0];
        short8 bf  = *(const short8*)&wbf[n0 * DIM + k0];   // B[k][n]=W[n][k]
        acc0 = __builtin_amdgcn_mfma_f32_16x16x32_bf16(af0, bf, acc0, 0, 0, 0);
        acc1 = __builtin_amdgcn_mfma_f32_16x16x32_bf16(af1, bf, acc1, 0, 0, 0);
    }
    __syncthreads();               // rowsbuf dead

    // C/D layout: lane holds D[m=quad*4+r][n=l15] -> stage to Cbuf (+bias)
    #pragma unroll
    for (int r = 0; r < 4; ++r) {
        int m = quad * 4 + r;
        Cbuf[m * 132 + n0]        = acc0[r] + bb;
        Cbuf[(m + 16) * 132 + n0] = acc1[r] + bb;
    }
    __syncthreads();

    // ---- P5: ReLU + LN + scale/offset -> out (4 rows per wave) ----
    const float sc0 = scale[lane],  sc1 = scale[lane + 64];
    const float of0 = offset[lane], of1 = offset[lane + 64];

    #pragma unroll
    for (int j = 0; j < 4; ++j) {
        int rl = rb + j;
        int r  = hb * 32 + rl;
        if (r >= N_NODES) continue;                       // wave-uniform
        float A0 = fmaxf(Cbuf[rl * 132 + lane],      0.0f);
        float A1 = fmaxf(Cbuf[rl * 132 + lane + 64], 0.0f);

        float s = A0 + A1;
        #pragma unroll
        for (int off = 32; off >= 1; off >>= 1) s += __shfl_xor(s, off, 64);
        float mean = s * (1.0f / 128.0f);

        float d0 = A0 - mean, d1 = A1 - mean;
        float q2 = d0 * d0 + d1 * d1;
        #pragma unroll
        for (int off = 32; off >= 1; off >>= 1) q2 += __shfl_xor(q2, off, 64);
        float rstd = rsqrtf(q2 * (1.0f / 128.0f) + LN_EPS);

        size_t rowp = (size_t)r * DIM;
        out[rowp + lane]      = d0 * sc0 * rstd + of0;
        out[rowp + lane + 64] = d1 * sc1 * rstd + of1;
    }
}

extern "C" void kernel_launch(void* const* d_in, const int* in_sizes, int n_in,
                              void* d_out, int out_size, void* d_ws, size_t ws_size,
                              hipStream_t stream) {
    const float* feat_in = (const float*)d_in[0];
    const int*   rows    = (const int*)d_in[1];
    const int*   cols    = (const int*)d_in[2];
    const float* vals    = (const float*)d_in[3];
    const float* W       = (const float*)d_in[4];
    const float* bias    = (const float*)d_in[5];
    const float* scale   = (const float*)d_in[6];
    const float* offset  = (const float*)d_in[7];
    float* out = (float*)d_out;

    // ---- workspace layout ----
    char* p = (char*)d_ws;
    int2* perm = (int2*)p;                 p += (size_t)NB2 * CAP2 * 8;        // 16.0 MB
    ushort* featb = (ushort*)p;            p += (size_t)N_NODES * DIM * 2;     // 12.8 MB
    ushort* wbf = (ushort*)p;              p += DIM * DIM * 2;                 // 32 KB
    int*  gcnt = (int*)p;                  p += (size_t)(NB2 + 64) * 4;        // 6.4 KB

    hipMemsetAsync(gcnt, 0, (size_t)NB2 * sizeof(int), stream);

    prep<<<SB + CONVB, 1024, 0, stream>>>(feat_in, W, rows, cols, vals,
                                          gcnt, perm, (uint*)featb, wbf);
    agg_fused<<<NB2, 512, 0, stream>>>(perm, gcnt, featb, wbf,
                                       bias, scale, offset, out);
}